// Round 6
// baseline (247.569 us; speedup 1.0000x reference)
//
#include <hip/hip_runtime.h>
#include <math.h>

#define KB 16

// Native clang vector type — required for __builtin_nontemporal_store.
typedef float vf4 __attribute__((ext_vector_type(4)));

// Per-element core. Faithful fp32 op order vs reference (__f*_rn blocks FMA
// contraction; rintf == round-half-even == jnp.round). Division by alpha is
// multiply by precomputed 1/alpha — bit-exact for pow2 alpha (bench: 1.0).
// Table holds pv[m] = __fmul_rn(alpha, zval[m]) — same operands/op as the
// reference's final alpha-multiply -> bit-identical (R4/R5: absmax 0.0);
// high path alpha*1.0 == alpha exactly.
__device__ __forceinline__ float lcq_core(float xv, float alpha, float rcp_alpha,
                                          const float2* __restrict__ s_gb,
                                          const float* __restrict__ s_pv)
{
    float a   = fabsf(xv);
    float xt  = __fmul_rn(a, rcp_alpha);            // x_tmp = |x|/alpha
    float t16 = __fmul_rn(xt, 16.0f);               // exact pow2 scale
    float jf  = fminf(t16, 15.0f);
    int   j   = (int)jf;                            // searchsorted(dst,·,right)-1
    float2 gb = s_gb[j];                            // ds_read_b64, conflict-free
    float dj  = __fmul_rn(floorf(jf), 0.0625f);     // dst[j] = j/16, exact
    float y   = __fadd_rn(__fmul_rn(gb.x, __fsub_rn(xt, dj)), gb.y);
    float t   = rintf(__fmul_rn(y, 15.0f));         // m = round(y*s), half-even; t>=0
    int   m   = (int)fminf(t, 15.0f);
    float r   = (a < alpha) ? s_pv[m] : alpha;      // flag select, alpha pre-folded
    return copysignf(r, xv);                        // x==0 -> 0 (pv[0]==0)
}

// Geometry: champion structure — 8192 one-shot blocks, each owns float4
// indices [b*1024,(b+1)*1024) (16KB read + 16KB write), 4 loads -> 16 elems
// -> 4 NT stores, retire. Load-first prologue kept from R5 (neutral but
// harmless; hides HBM latency under table setup).
//
// ROUND 6 single change: loads NT -> PLAIN. Evidence: with plain loads the
// LLC serves ~half the input (R2/R4: FETCH_SIZE 65.7MB of 134MB). R2's
// slowdown (plain/plain, 86us) is attributed to plain STORES write-allocating
// 131MB of output through L2/LLC — evicting the input lines and occupying the
// cache pipe — not to plain loads. NT stores (kept) bypass the caches, so
// plain loads should harvest the LLC hits: HBM traffic 262 -> ~197MB.
__global__ __launch_bounds__(256) void lcq_kernel(
    const float* __restrict__ x,
    const float* __restrict__ thr,
    const float* __restrict__ theta,
    float* __restrict__ out,
    long long n)
{
    __shared__ float2 s_gb[KB];     // (gamma[j], beta[j])
    __shared__ float  s_pv[KB];     // alpha * expand(m/15)
    __shared__ float  s_scal[2];    // alpha, 1/alpha

    const long long n4ll = n >> 2;
    const vf4* __restrict__ x4 = (const vf4*)x;
    vf4* __restrict__ o4 = (vf4*)out;

    const unsigned base = blockIdx.x * 1024u + threadIdx.x;  // float4 index
    const bool full = ((long long)(blockIdx.x + 1) * 1024ll <= n4ll);

    // ---- (1) issue input loads first (independent of tables) ----
    vf4 v0, v1, v2, v3;
    if (full) {
        v0 = x4[base];
        v1 = x4[base + 256u];
        v2 = x4[base + 512u];
        v3 = x4[base + 768u];
    }

    // ---- (2) table setup overlaps the load latency ----
    if (threadIdx.x == 0) {
        // softmax(theta), fp32, sequential order (bit-matched all rounds)
        float th[KB];
        float mx = theta[0];
        th[0] = mx;
        #pragma unroll
        for (int i = 1; i < KB; ++i) { th[i] = theta[i]; mx = fmaxf(mx, th[i]); }
        float ex[KB];
        float sum = 0.0f;
        #pragma unroll
        for (int i = 0; i < KB; ++i) { ex[i] = expf(__fsub_rn(th[i], mx)); sum = __fadd_rn(sum, ex[i]); }
        float sm[KB];
        #pragma unroll
        for (int i = 0; i < KB; ++i) sm[i] = __fdiv_rn(ex[i], sum);

        float beta[KB], gamma[KB];
        beta[0] = 0.0f;
        float c = sm[0];
        #pragma unroll
        for (int i = 1; i < KB; ++i) { beta[i] = c; c = __fadd_rn(c, sm[i]); }
        #pragma unroll
        for (int i = 0; i < KB; ++i) gamma[i] = __fmul_rn(sm[i], 16.0f);

        #pragma unroll
        for (int i = 0; i < KB; ++i) s_gb[i] = make_float2(gamma[i], beta[i]);

        float alpha = thr[0];
        s_scal[0] = alpha;
        s_scal[1] = __fdiv_rn(1.0f, alpha);  // exact for pow2 alpha (bench: 1.0)

        // pv[m] = alpha * expand(m/15): searchsorted + inverse affine, then
        // the reference's alpha-multiply pre-folded (same operands -> same bits)
        for (int m = 0; m < KB; ++m) {
            float yq = __fdiv_rn((float)m, 15.0f);
            int iq = 0;
            #pragma unroll
            for (int i = 1; i < KB; ++i) iq += (beta[i] <= yq) ? 1 : 0;
            float zv = __fadd_rn(__fdiv_rn(__fsub_rn(yq, beta[iq]), gamma[iq]),
                                 (float)iq * 0.0625f);
            s_pv[m] = __fmul_rn(alpha, zv);
        }
    }
    __syncthreads();   // loads issued ~1200cy ago have landed by the drain

    const float alpha = s_scal[0];
    const float rcpa  = s_scal[1];

    // ---- (3) compute + NT stores ----
    if (full) {
        vf4 r0, r1, r2, r3;
        r0.x = lcq_core(v0.x, alpha, rcpa, s_gb, s_pv);
        r0.y = lcq_core(v0.y, alpha, rcpa, s_gb, s_pv);
        r0.z = lcq_core(v0.z, alpha, rcpa, s_gb, s_pv);
        r0.w = lcq_core(v0.w, alpha, rcpa, s_gb, s_pv);
        r1.x = lcq_core(v1.x, alpha, rcpa, s_gb, s_pv);
        r1.y = lcq_core(v1.y, alpha, rcpa, s_gb, s_pv);
        r1.z = lcq_core(v1.z, alpha, rcpa, s_gb, s_pv);
        r1.w = lcq_core(v1.w, alpha, rcpa, s_gb, s_pv);
        r2.x = lcq_core(v2.x, alpha, rcpa, s_gb, s_pv);
        r2.y = lcq_core(v2.y, alpha, rcpa, s_gb, s_pv);
        r2.z = lcq_core(v2.z, alpha, rcpa, s_gb, s_pv);
        r2.w = lcq_core(v2.w, alpha, rcpa, s_gb, s_pv);
        r3.x = lcq_core(v3.x, alpha, rcpa, s_gb, s_pv);
        r3.y = lcq_core(v3.y, alpha, rcpa, s_gb, s_pv);
        r3.z = lcq_core(v3.z, alpha, rcpa, s_gb, s_pv);
        r3.w = lcq_core(v3.w, alpha, rcpa, s_gb, s_pv);
        __builtin_nontemporal_store(r0, &o4[base]);
        __builtin_nontemporal_store(r1, &o4[base + 256u]);
        __builtin_nontemporal_store(r2, &o4[base + 512u]);
        __builtin_nontemporal_store(r3, &o4[base + 768u]);
    } else {
        // Partial last block (not hit at bench shape; kept for generality).
        #pragma unroll
        for (int k = 0; k < 4; ++k) {
            long long i = (long long)base + k * 256;
            if (i < n4ll) {
                vf4 v = x4[i];
                vf4 r;
                r.x = lcq_core(v.x, alpha, rcpa, s_gb, s_pv);
                r.y = lcq_core(v.y, alpha, rcpa, s_gb, s_pv);
                r.z = lcq_core(v.z, alpha, rcpa, s_gb, s_pv);
                r.w = lcq_core(v.w, alpha, rcpa, s_gb, s_pv);
                o4[i] = r;
            }
        }
        // scalar remainder (n % 4), handled by the last block only
        if (blockIdx.x == gridDim.x - 1) {
            for (long long k = (n4ll << 2) + threadIdx.x; k < n; k += 256) {
                out[k] = lcq_core(x[k], alpha, rcpa, s_gb, s_pv);
            }
        }
    }
}

extern "C" void kernel_launch(void* const* d_in, const int* in_sizes, int n_in,
                              void* d_out, int out_size, void* d_ws, size_t ws_size,
                              hipStream_t stream) {
    const float* x     = (const float*)d_in[0];   // (4,4096,2048) fp32
    const float* thr   = (const float*)d_in[1];   // (1,) alpha
    const float* theta = (const float*)d_in[2];   // (16,)
    float* out = (float*)d_out;

    long long n = (long long)in_sizes[0];
    long long n4 = n >> 2;
    long long grid = (n4 + 1023) / 1024;          // bench: 8192 one-shot blocks
    if (grid < 1) grid = 1;
    dim3 block(256);
    hipLaunchKernelGGL(lcq_kernel, dim3((unsigned)grid), block, 0, stream,
                       x, thr, theta, out, n);
}

// Round 8
// 234.364 us; speedup vs baseline: 1.0563x; 1.0563x over previous
//
#include <hip/hip_runtime.h>
#include <math.h>

#define KB 16

// Native clang vector type — required for __builtin_nontemporal_load/store.
typedef float vf4 __attribute__((ext_vector_type(4)));

// Per-element core. Faithful fp32 op order vs reference (__f*_rn blocks FMA
// contraction; rintf == round-half-even == jnp.round). Division by alpha is
// multiply by precomputed 1/alpha — bit-exact for pow2 alpha (bench: 1.0).
// Table holds pv[m] = __fmul_rn(alpha, zval[m]) — same operands/op as the
// reference's final alpha-multiply -> bit-identical (R4/R5/R6: absmax 0.0);
// high path alpha*1.0 == alpha exactly.
__device__ __forceinline__ float lcq_core(float xv, float alpha, float rcp_alpha,
                                          const float2* __restrict__ s_gb,
                                          const float* __restrict__ s_pv)
{
    float a   = fabsf(xv);
    float xt  = __fmul_rn(a, rcp_alpha);            // x_tmp = |x|/alpha
    float t16 = __fmul_rn(xt, 16.0f);               // exact pow2 scale
    float jf  = fminf(t16, 15.0f);
    int   j   = (int)jf;                            // searchsorted(dst,·,right)-1
    float2 gb = s_gb[j];                            // ds_read_b64, conflict-free
    float dj  = __fmul_rn(floorf(jf), 0.0625f);     // dst[j] = j/16, exact
    float y   = __fadd_rn(__fmul_rn(gb.x, __fsub_rn(xt, dj)), gb.y);
    float t   = rintf(__fmul_rn(y, 15.0f));         // m = round(y*s), half-even; t>=0
    int   m   = (int)fminf(t, 15.0f);
    float r   = (a < alpha) ? s_pv[m] : alpha;      // flag select, alpha pre-folded
    return copysignf(r, xv);                        // x==0 -> 0 (pv[0]==0)
}

// ROUND 8 (= R7 resubmit; R7 was an infra failure, hypothesis untested).
// NT/NT is settled champion (R6 completed the A/B matrix: NT loads are
// load-bearing — plain loads LOST despite 65MB fewer HBM bytes and confirmed
// LLC hits; traffic volume is exonerated, load-path is king).
// Single change vs champion: 32KB one-shot blocks — 8 NT loads ALL issued
// up-front, then 32 elems compute, then 8 NT stores, retire. Doubles
// per-wave in-flight bytes (64->128 B/lane) and halves block count (4096).
// Unlike R4's failed ping-pong, stores NEVER interleave between load issue
// and load consumption, so vmcnt waits for load data are not entangled with
// outstanding stores. One-shot retire semantics preserved.
__global__ __launch_bounds__(256) void lcq_kernel(
    const float* __restrict__ x,
    const float* __restrict__ thr,
    const float* __restrict__ theta,
    float* __restrict__ out,
    long long n)
{
    __shared__ float2 s_gb[KB];     // (gamma[j], beta[j])
    __shared__ float  s_pv[KB];     // alpha * expand(m/15)
    __shared__ float  s_scal[2];    // alpha, 1/alpha

    const long long n4ll = n >> 2;
    const vf4* __restrict__ x4 = (const vf4*)x;
    vf4* __restrict__ o4 = (vf4*)out;

    const unsigned base = blockIdx.x * 2048u + threadIdx.x;  // float4 index
    const bool full = ((long long)(blockIdx.x + 1) * 2048ll <= n4ll);

    // ---- (1) issue ALL 8 input loads first (independent of tables) ----
    vf4 v0, v1, v2, v3, v4, v5, v6, v7;
    if (full) {
        v0 = __builtin_nontemporal_load(&x4[base]);
        v1 = __builtin_nontemporal_load(&x4[base +  256u]);
        v2 = __builtin_nontemporal_load(&x4[base +  512u]);
        v3 = __builtin_nontemporal_load(&x4[base +  768u]);
        v4 = __builtin_nontemporal_load(&x4[base + 1024u]);
        v5 = __builtin_nontemporal_load(&x4[base + 1280u]);
        v6 = __builtin_nontemporal_load(&x4[base + 1536u]);
        v7 = __builtin_nontemporal_load(&x4[base + 1792u]);
    }

    // ---- (2) table setup overlaps the load latency ----
    if (threadIdx.x == 0) {
        // softmax(theta), fp32, sequential order (bit-matched all rounds)
        float th[KB];
        float mx = theta[0];
        th[0] = mx;
        #pragma unroll
        for (int i = 1; i < KB; ++i) { th[i] = theta[i]; mx = fmaxf(mx, th[i]); }
        float ex[KB];
        float sum = 0.0f;
        #pragma unroll
        for (int i = 0; i < KB; ++i) { ex[i] = expf(__fsub_rn(th[i], mx)); sum = __fadd_rn(sum, ex[i]); }
        float sm[KB];
        #pragma unroll
        for (int i = 0; i < KB; ++i) sm[i] = __fdiv_rn(ex[i], sum);

        float beta[KB], gamma[KB];
        beta[0] = 0.0f;
        float c = sm[0];
        #pragma unroll
        for (int i = 1; i < KB; ++i) { beta[i] = c; c = __fadd_rn(c, sm[i]); }
        #pragma unroll
        for (int i = 0; i < KB; ++i) gamma[i] = __fmul_rn(sm[i], 16.0f);

        #pragma unroll
        for (int i = 0; i < KB; ++i) s_gb[i] = make_float2(gamma[i], beta[i]);

        float alpha = thr[0];
        s_scal[0] = alpha;
        s_scal[1] = __fdiv_rn(1.0f, alpha);  // exact for pow2 alpha (bench: 1.0)

        // pv[m] = alpha * expand(m/15): searchsorted + inverse affine, then
        // the reference's alpha-multiply pre-folded (same operands -> same bits)
        for (int m = 0; m < KB; ++m) {
            float yq = __fdiv_rn((float)m, 15.0f);
            int iq = 0;
            #pragma unroll
            for (int i = 1; i < KB; ++i) iq += (beta[i] <= yq) ? 1 : 0;
            float zv = __fadd_rn(__fdiv_rn(__fsub_rn(yq, beta[iq]), gamma[iq]),
                                 (float)iq * 0.0625f);
            s_pv[m] = __fmul_rn(alpha, zv);
        }
    }
    __syncthreads();   // loads issued ~1200cy ago are landing by the drain

    const float alpha = s_scal[0];
    const float rcpa  = s_scal[1];

    // ---- (3) compute + NT stores (loads consumed in issue order; the
    //          compiler retires them with descending vmcnt waits) ----
    if (full) {
        vf4 r0, r1, r2, r3, r4, r5, r6, r7;
#define LCQ_C4(R, V) \
        R.x = lcq_core(V.x, alpha, rcpa, s_gb, s_pv); \
        R.y = lcq_core(V.y, alpha, rcpa, s_gb, s_pv); \
        R.z = lcq_core(V.z, alpha, rcpa, s_gb, s_pv); \
        R.w = lcq_core(V.w, alpha, rcpa, s_gb, s_pv);
        LCQ_C4(r0, v0)
        LCQ_C4(r1, v1)
        LCQ_C4(r2, v2)
        LCQ_C4(r3, v3)
        LCQ_C4(r4, v4)
        LCQ_C4(r5, v5)
        LCQ_C4(r6, v6)
        LCQ_C4(r7, v7)
#undef LCQ_C4
        __builtin_nontemporal_store(r0, &o4[base]);
        __builtin_nontemporal_store(r1, &o4[base +  256u]);
        __builtin_nontemporal_store(r2, &o4[base +  512u]);
        __builtin_nontemporal_store(r3, &o4[base +  768u]);
        __builtin_nontemporal_store(r4, &o4[base + 1024u]);
        __builtin_nontemporal_store(r5, &o4[base + 1280u]);
        __builtin_nontemporal_store(r6, &o4[base + 1536u]);
        __builtin_nontemporal_store(r7, &o4[base + 1792u]);
    } else {
        // Partial last block (not hit at bench shape; kept for generality).
        #pragma unroll
        for (int k = 0; k < 8; ++k) {
            long long i = (long long)base + k * 256;
            if (i < n4ll) {
                vf4 v = x4[i];
                vf4 r;
                r.x = lcq_core(v.x, alpha, rcpa, s_gb, s_pv);
                r.y = lcq_core(v.y, alpha, rcpa, s_gb, s_pv);
                r.z = lcq_core(v.z, alpha, rcpa, s_gb, s_pv);
                r.w = lcq_core(v.w, alpha, rcpa, s_gb, s_pv);
                o4[i] = r;
            }
        }
        // scalar remainder (n % 4), handled by the last block only
        if (blockIdx.x == gridDim.x - 1) {
            for (long long k = (n4ll << 2) + threadIdx.x; k < n; k += 256) {
                out[k] = lcq_core(x[k], alpha, rcpa, s_gb, s_pv);
            }
        }
    }
}

extern "C" void kernel_launch(void* const* d_in, const int* in_sizes, int n_in,
                              void* d_out, int out_size, void* d_ws, size_t ws_size,
                              hipStream_t stream) {
    const float* x     = (const float*)d_in[0];   // (4,4096,2048) fp32
    const float* thr   = (const float*)d_in[1];   // (1,) alpha
    const float* theta = (const float*)d_in[2];   // (16,)
    float* out = (float*)d_out;

    long long n = (long long)in_sizes[0];
    long long n4 = n >> 2;
    long long grid = (n4 + 2047) / 2048;          // bench: 4096 one-shot blocks
    if (grid < 1) grid = 1;
    dim3 block(256);
    hipLaunchKernelGGL(lcq_kernel, dim3((unsigned)grid), block, 0, stream,
                       x, thr, theta, out, n);
}